// Round 1
// baseline (379.081 us; speedup 1.0000x reference)
//
#include <hip/hip_runtime.h>
#include <hip/hip_bf16.h>

#define N_ELEM 1000000
#define D 128
#define S_SEG 65536

// Order-preserving monotone encoding of float -> unsigned for atomicMax.
__device__ __forceinline__ unsigned encf(float f) {
    unsigned u = __float_as_uint(f);
    return (u & 0x80000000u) ? ~u : (u | 0x80000000u);
}
__device__ __forceinline__ float decf(unsigned e) {
    return (e & 0x80000000u) ? __uint_as_float(e & 0x7fffffffu) : __uint_as_float(~e);
}

// K1: scores[i] = emb[i,:] . w_att ; segmax[seg] = max(scores)
// 32 lanes per element, float4 loads (512B per element, coalesced).
__global__ __launch_bounds__(256) void k_scores(
        const float* __restrict__ emb, const int* __restrict__ seg,
        const float* __restrict__ watt, float* __restrict__ scores,
        unsigned* __restrict__ segmax) {
    const int lane = threadIdx.x & 31;
    const int grp  = threadIdx.x >> 5;  // 0..7
    const float4 wv = reinterpret_cast<const float4*>(watt)[lane];
    const int stride = gridDim.x * 8;
    for (int e = blockIdx.x * 8 + grp; e < N_ELEM; e += stride) {
        float4 v = reinterpret_cast<const float4*>(emb + (size_t)e * D)[lane];
        float s = v.x * wv.x + v.y * wv.y + v.z * wv.z + v.w * wv.w;
        #pragma unroll
        for (int off = 16; off >= 1; off >>= 1)
            s += __shfl_xor(s, off, 64);
        if (lane == 0) {
            scores[e] = s;
            atomicMax(segmax + seg[e], encf(s));
        }
    }
}

// K2: segsum[s] = sum exp(score - max)
__global__ __launch_bounds__(256) void k_sumexp(
        const float* __restrict__ scores, const int* __restrict__ seg,
        const unsigned* __restrict__ segmax, float* __restrict__ segsum) {
    const int stride = gridDim.x * blockDim.x;
    for (int i = blockIdx.x * blockDim.x + threadIdx.x; i < N_ELEM; i += stride) {
        int s = seg[i];
        float m = decf(segmax[s]);
        atomicAdd(segsum + s, expf(scores[i] - m));
    }
}

// K3: scores[i] <- p_i = exp(score - max) / segsum   (in place)
__global__ __launch_bounds__(256) void k_probs(
        float* __restrict__ scores, const int* __restrict__ seg,
        const unsigned* __restrict__ segmax, const float* __restrict__ segsum) {
    const int stride = gridDim.x * blockDim.x;
    for (int i = blockIdx.x * blockDim.x + threadIdx.x; i < N_ELEM; i += stride) {
        int s = seg[i];
        float m = decf(segmax[s]);
        scores[i] = expf(scores[i] - m) / segsum[s];
    }
}

// K4: h[s,:] += p_i * emb[i,:]  accumulated into d_out via per-segment register
// accumulation (map is sorted). 128-thread group per 256-element chunk; thread d
// owns dimension d. Flush on segment change (atomicAdd covers chunk-boundary segs).
#define CH 256
__global__ __launch_bounds__(256) void k_wsum(
        const float* __restrict__ emb, const int* __restrict__ seg,
        const float* __restrict__ p, float* __restrict__ out) {
    const int d = threadIdx.x & 127;
    const int g = blockIdx.x * 2 + (threadIdx.x >> 7);
    const int base = g * CH;
    if (base >= N_ELEM) return;
    const int end = min(base + CH, N_ELEM);
    int cur = seg[base];
    float acc = 0.f;
    for (int e = base; e < end; e += 4) {
        float v[4], pp[4];
        int ss[4];
        #pragma unroll
        for (int j = 0; j < 4; ++j) {
            int ee = e + j;
            bool ok = ee < end;
            ss[j] = ok ? seg[ee] : -1;
            pp[j] = ok ? p[ee] : 0.f;
            v[j]  = ok ? emb[(size_t)ee * D + d] : 0.f;
        }
        #pragma unroll
        for (int j = 0; j < 4; ++j) {
            if (ss[j] < 0) break;  // tail padding
            if (ss[j] != cur) {
                atomicAdd(out + (size_t)cur * D + d, acc);
                acc = 0.f;
                cur = ss[j];
            }
            acc = fmaf(pp[j], v[j], acc);
        }
    }
    atomicAdd(out + (size_t)cur * D + d, acc);
}

// K5: out[s,:] = h[s,:] @ w_out^T, in place per 128-row tile.
// LDS-staged, transposed with +4 padding to dodge bank conflicts.
#define PAD 132
__global__ __launch_bounds__(256) void k_proj(
        float* __restrict__ out, const float* __restrict__ wout) {
    __shared__ float As[128 * PAD];  // As[k*PAD + r] = h[r0+r][k]
    __shared__ float Bs[128 * PAD];  // Bs[k*PAD + j] = wout[j][k]
    const int tid = threadIdx.x;
    const int r0 = blockIdx.x * 128;
    for (int idx = tid; idx < 128 * 128; idx += 256) {
        int a = idx >> 7, k = idx & 127;
        As[k * PAD + a] = out[(size_t)(r0 + a) * D + k];
        Bs[k * PAD + a] = wout[(size_t)a * D + k];
    }
    __syncthreads();
    const int tx = tid & 15, ty = tid >> 4;
    const int rr = ty * 8, cc = tx * 8;
    float acc[8][8] = {};
    for (int k = 0; k < 128; ++k) {
        float a[8], b[8];
        *reinterpret_cast<float4*>(&a[0]) = *reinterpret_cast<const float4*>(&As[k * PAD + rr]);
        *reinterpret_cast<float4*>(&a[4]) = *reinterpret_cast<const float4*>(&As[k * PAD + rr + 4]);
        *reinterpret_cast<float4*>(&b[0]) = *reinterpret_cast<const float4*>(&Bs[k * PAD + cc]);
        *reinterpret_cast<float4*>(&b[4]) = *reinterpret_cast<const float4*>(&Bs[k * PAD + cc + 4]);
        #pragma unroll
        for (int i = 0; i < 8; ++i)
            #pragma unroll
            for (int j = 0; j < 8; ++j)
                acc[i][j] = fmaf(a[i], b[j], acc[i][j]);
    }
    #pragma unroll
    for (int i = 0; i < 8; ++i) {
        float4 o0 = {acc[i][0], acc[i][1], acc[i][2], acc[i][3]};
        float4 o1 = {acc[i][4], acc[i][5], acc[i][6], acc[i][7]};
        *reinterpret_cast<float4*>(&out[(size_t)(r0 + rr + i) * D + cc])     = o0;
        *reinterpret_cast<float4*>(&out[(size_t)(r0 + rr + i) * D + cc + 4]) = o1;
    }
}

extern "C" void kernel_launch(void* const* d_in, const int* in_sizes, int n_in,
                              void* d_out, int out_size, void* d_ws, size_t ws_size,
                              hipStream_t stream) {
    const float* emb  = (const float*)d_in[0];
    const int*   seg  = (const int*)d_in[1];
    const float* watt = (const float*)d_in[3];
    const float* wout = (const float*)d_in[4];
    float* out = (float*)d_out;

    // Workspace layout: scores[N] f32 | segmax[S] u32 | segsum[S] f32  (~4.5 MB)
    float*    scores = (float*)d_ws;
    unsigned* segmax = (unsigned*)((char*)d_ws + (size_t)N_ELEM * 4);
    float*    segsum = (float*)((char*)d_ws + (size_t)N_ELEM * 4 + (size_t)S_SEG * 4);

    hipMemsetAsync(segmax, 0, (size_t)S_SEG * 4 * 2, stream);       // segmax=enc(-inf)-safe, segsum=0
    hipMemsetAsync(d_out, 0, (size_t)S_SEG * D * 4, stream);        // h accumulator

    k_scores<<<2048, 256, 0, stream>>>(emb, seg, watt, scores, segmax);
    k_sumexp<<<2048, 256, 0, stream>>>(scores, seg, segmax, segsum);
    k_probs <<<2048, 256, 0, stream>>>(scores, seg, segmax, segsum);
    const int n_groups = (N_ELEM + CH - 1) / CH;            // 3907
    k_wsum  <<<(n_groups + 1) / 2, 256, 0, stream>>>(emb, seg, scores, out);
    k_proj  <<<S_SEG / 128, 256, 0, stream>>>(out, wout);
}

// Round 2
// 377.871 us; speedup vs baseline: 1.0032x; 1.0032x over previous
//
#include <hip/hip_runtime.h>
#include <hip/hip_bf16.h>

#define N_ELEM 1000000
#define D 128
#define S_SEG 65536

// Order-preserving monotone encoding of float -> unsigned for atomicMax.
__device__ __forceinline__ unsigned encf(float f) {
    unsigned u = __float_as_uint(f);
    return (u & 0x80000000u) ? ~u : (u | 0x80000000u);
}
__device__ __forceinline__ float decf(unsigned e) {
    return (e & 0x80000000u) ? __uint_as_float(e & 0x7fffffffu) : __uint_as_float(~e);
}

// K0: fast zero fill (the rocclr fillBuffer kernel was 290 us @ 115 GB/s!)
__global__ __launch_bounds__(256) void k_zero(float4* __restrict__ p, int n4) {
    const int stride = gridDim.x * blockDim.x;
    const float4 z = {0.f, 0.f, 0.f, 0.f};
    for (int i = blockIdx.x * blockDim.x + threadIdx.x; i < n4; i += stride)
        p[i] = z;
}

// K1: scores[i] = emb[i,:] . w_att ; segmax[seg] = max(scores)
// 32 lanes per element, float4 loads (512B per element, coalesced).
__global__ __launch_bounds__(256) void k_scores(
        const float* __restrict__ emb, const int* __restrict__ seg,
        const float* __restrict__ watt, float* __restrict__ scores,
        unsigned* __restrict__ segmax) {
    const int lane = threadIdx.x & 31;
    const int grp  = threadIdx.x >> 5;  // 0..7
    const float4 wv = reinterpret_cast<const float4*>(watt)[lane];
    const int stride = gridDim.x * 8;
    for (int e = blockIdx.x * 8 + grp; e < N_ELEM; e += stride) {
        float4 v = reinterpret_cast<const float4*>(emb + (size_t)e * D)[lane];
        float s = v.x * wv.x + v.y * wv.y + v.z * wv.z + v.w * wv.w;
        #pragma unroll
        for (int off = 16; off >= 1; off >>= 1)
            s += __shfl_xor(s, off, 64);
        if (lane == 0) {
            scores[e] = s;
            atomicMax(segmax + seg[e], encf(s));
        }
    }
}

// K2: segsum[s] = sum exp(score - max)
__global__ __launch_bounds__(256) void k_sumexp(
        const float* __restrict__ scores, const int* __restrict__ seg,
        const unsigned* __restrict__ segmax, float* __restrict__ segsum) {
    const int stride = gridDim.x * blockDim.x;
    for (int i = blockIdx.x * blockDim.x + threadIdx.x; i < N_ELEM; i += stride) {
        int s = seg[i];
        float m = decf(segmax[s]);
        atomicAdd(segsum + s, expf(scores[i] - m));
    }
}

// K3: scores[i] <- p_i = exp(score - max) / segsum   (in place)
__global__ __launch_bounds__(256) void k_probs(
        float* __restrict__ scores, const int* __restrict__ seg,
        const unsigned* __restrict__ segmax, const float* __restrict__ segsum) {
    const int stride = gridDim.x * blockDim.x;
    for (int i = blockIdx.x * blockDim.x + threadIdx.x; i < N_ELEM; i += stride) {
        int s = seg[i];
        float m = decf(segmax[s]);
        scores[i] = expf(scores[i] - m) / segsum[s];
    }
}

// K4: h[s,:] += p_i * emb[i,:]  accumulated into d_out via per-segment register
// accumulation (map is sorted). 128-thread group per 256-element chunk; thread d
// owns dimension d. Flush on segment change (atomicAdd covers chunk-boundary segs).
#define CH 256
__global__ __launch_bounds__(256) void k_wsum(
        const float* __restrict__ emb, const int* __restrict__ seg,
        const float* __restrict__ p, float* __restrict__ out) {
    const int d = threadIdx.x & 127;
    const int g = blockIdx.x * 2 + (threadIdx.x >> 7);
    const int base = g * CH;
    if (base >= N_ELEM) return;
    const int end = min(base + CH, N_ELEM);
    int cur = seg[base];
    float acc = 0.f;
    for (int e = base; e < end; e += 4) {
        float v[4], pp[4];
        int ss[4];
        #pragma unroll
        for (int j = 0; j < 4; ++j) {
            int ee = e + j;
            bool ok = ee < end;
            ss[j] = ok ? seg[ee] : -1;
            pp[j] = ok ? p[ee] : 0.f;
            v[j]  = ok ? emb[(size_t)ee * D + d] : 0.f;
        }
        #pragma unroll
        for (int j = 0; j < 4; ++j) {
            if (ss[j] < 0) break;  // tail padding
            if (ss[j] != cur) {
                atomicAdd(out + (size_t)cur * D + d, acc);
                acc = 0.f;
                cur = ss[j];
            }
            acc = fmaf(pp[j], v[j], acc);
        }
    }
    atomicAdd(out + (size_t)cur * D + d, acc);
}

// K5: out[s,:] = h[s,:] @ w_out^T, in place per 128-row tile.
// LDS-staged, transposed with +4 padding to dodge bank conflicts.
#define PAD 132
__global__ __launch_bounds__(256) void k_proj(
        float* __restrict__ out, const float* __restrict__ wout) {
    __shared__ float As[128 * PAD];  // As[k*PAD + r] = h[r0+r][k]
    __shared__ float Bs[128 * PAD];  // Bs[k*PAD + j] = wout[j][k]
    const int tid = threadIdx.x;
    const int r0 = blockIdx.x * 128;
    for (int idx = tid; idx < 128 * 128; idx += 256) {
        int a = idx >> 7, k = idx & 127;
        As[k * PAD + a] = out[(size_t)(r0 + a) * D + k];
        Bs[k * PAD + a] = wout[(size_t)a * D + k];
    }
    __syncthreads();
    const int tx = tid & 15, ty = tid >> 4;
    const int rr = ty * 8, cc = tx * 8;
    float acc[8][8] = {};
    for (int k = 0; k < 128; ++k) {
        float a[8], b[8];
        *reinterpret_cast<float4*>(&a[0]) = *reinterpret_cast<const float4*>(&As[k * PAD + rr]);
        *reinterpret_cast<float4*>(&a[4]) = *reinterpret_cast<const float4*>(&As[k * PAD + rr + 4]);
        *reinterpret_cast<float4*>(&b[0]) = *reinterpret_cast<const float4*>(&Bs[k * PAD + cc]);
        *reinterpret_cast<float4*>(&b[4]) = *reinterpret_cast<const float4*>(&Bs[k * PAD + cc + 4]);
        #pragma unroll
        for (int i = 0; i < 8; ++i)
            #pragma unroll
            for (int j = 0; j < 8; ++j)
                acc[i][j] = fmaf(a[i], b[j], acc[i][j]);
    }
    #pragma unroll
    for (int i = 0; i < 8; ++i) {
        float4 o0 = {acc[i][0], acc[i][1], acc[i][2], acc[i][3]};
        float4 o1 = {acc[i][4], acc[i][5], acc[i][6], acc[i][7]};
        *reinterpret_cast<float4*>(&out[(size_t)(r0 + rr + i) * D + cc])     = o0;
        *reinterpret_cast<float4*>(&out[(size_t)(r0 + rr + i) * D + cc + 4]) = o1;
    }
}

extern "C" void kernel_launch(void* const* d_in, const int* in_sizes, int n_in,
                              void* d_out, int out_size, void* d_ws, size_t ws_size,
                              hipStream_t stream) {
    const float* emb  = (const float*)d_in[0];
    const int*   seg  = (const int*)d_in[1];
    const float* watt = (const float*)d_in[3];
    const float* wout = (const float*)d_in[4];
    float* out = (float*)d_out;

    // Workspace layout: scores[N] f32 | segmax[S] u32 | segsum[S] f32  (~4.5 MB)
    float*    scores = (float*)d_ws;
    unsigned* segmax = (unsigned*)((char*)d_ws + (size_t)N_ELEM * 4);
    float*    segsum = (float*)((char*)d_ws + (size_t)N_ELEM * 4 + (size_t)S_SEG * 4);

    // Fast zero-init: segmax+segsum (contiguous, 512 KB) and d_out (33.5 MB).
    // (hipMemsetAsync's fill kernel ran at ~115 GB/s and cost 290 us.)
    k_zero<<<128, 256, 0, stream>>>((float4*)segmax, (2 * S_SEG) / 4);
    k_zero<<<2048, 256, 0, stream>>>((float4*)out, (S_SEG * D) / 4);

    k_scores<<<2048, 256, 0, stream>>>(emb, seg, watt, scores, segmax);
    k_sumexp<<<2048, 256, 0, stream>>>(scores, seg, segmax, segsum);
    k_probs <<<2048, 256, 0, stream>>>(scores, seg, segmax, segsum);
    const int n_groups = (N_ELEM + CH - 1) / CH;            // 3907
    k_wsum  <<<(n_groups + 1) / 2, 256, 0, stream>>>(emb, seg, scores, out);
    k_proj  <<<S_SEG / 128, 256, 0, stream>>>(out, wout);
}

// Round 3
// 337.127 us; speedup vs baseline: 1.1244x; 1.1209x over previous
//
#include <hip/hip_runtime.h>
#include <hip/hip_bf16.h>

#define N_ELEM 1000000
#define D 128
#define S_SEG 65536
#define WCH 64                      // elements per k_wsum group-chunk (N_ELEM % WCH == 0)

// Order-preserving monotone encoding of float -> unsigned for atomicMax.
// encf(x) > 0 for every finite x, so zero-init of segmax is a safe -inf.
__device__ __forceinline__ unsigned encf(float f) {
    unsigned u = __float_as_uint(f);
    return (u & 0x80000000u) ? ~u : (u | 0x80000000u);
}
__device__ __forceinline__ float decf(unsigned e) {
    return (e & 0x80000000u) ? __uint_as_float(e & 0x7fffffffu) : __uint_as_float(~e);
}

// K0: fast zero fill (runtime fillBuffer is fine for small, but keep it uniform)
__global__ __launch_bounds__(256) void k_zero(float4* __restrict__ p, int n4) {
    const int stride = gridDim.x * blockDim.x;
    const float4 z = {0.f, 0.f, 0.f, 0.f};
    for (int i = blockIdx.x * blockDim.x + threadIdx.x; i < n4; i += stride)
        p[i] = z;
}

// K1: scores[i] = emb[i,:] . w_att ; segmax[seg] = max(scores)
// 32 lanes per element, float4 loads; 2 elements per group per iter for ILP.
__global__ __launch_bounds__(256) void k_scores(
        const float* __restrict__ emb, const int* __restrict__ seg,
        const float* __restrict__ watt, float* __restrict__ scores,
        unsigned* __restrict__ segmax) {
    const int lane = threadIdx.x & 31;
    const int grp  = threadIdx.x >> 5;  // 0..7
    const float4 wv = reinterpret_cast<const float4*>(watt)[lane];
    const float4* emb4 = reinterpret_cast<const float4*>(emb);
    const int stride = gridDim.x * 16;
    for (int e = blockIdx.x * 16 + grp * 2; e < N_ELEM; e += stride) {
        // e is even, N even -> e+1 < N always
        float4 v0 = emb4[(size_t)e * 32 + lane];
        float4 v1 = emb4[(size_t)(e + 1) * 32 + lane];
        float s0 = v0.x * wv.x + v0.y * wv.y + v0.z * wv.z + v0.w * wv.w;
        float s1 = v1.x * wv.x + v1.y * wv.y + v1.z * wv.z + v1.w * wv.w;
        #pragma unroll
        for (int off = 16; off >= 1; off >>= 1) {
            s0 += __shfl_xor(s0, off, 64);   // xor<=16 stays within the 32-lane half
            s1 += __shfl_xor(s1, off, 64);
        }
        if (lane == 0) {
            float2 st = {s0, s1};
            *reinterpret_cast<float2*>(scores + e) = st;   // e even -> 8B aligned
            int g0 = seg[e], g1 = seg[e + 1];
            if (g0 == g1) {
                atomicMax(segmax + g0, encf(fmaxf(s0, s1)));
            } else {
                atomicMax(segmax + g0, encf(s0));
                atomicMax(segmax + g1, encf(s1));
            }
        }
    }
}

// K2: segsum[s] = sum exp(score - max), wave-segmented reduction.
// seg is SORTED, so equal-seg runs are contiguous within a wave.
// N_ELEM % 64 == 0 and stride % 64 == 0 -> every wave fully active, shfl safe.
__global__ __launch_bounds__(256) void k_sumexp(
        const float* __restrict__ scores, const int* __restrict__ seg,
        const unsigned* __restrict__ segmax, float* __restrict__ segsum) {
    const int lane = threadIdx.x & 63;
    const int stride = gridDim.x * blockDim.x;
    for (int i = blockIdx.x * blockDim.x + threadIdx.x; i < N_ELEM; i += stride) {
        int s = seg[i];
        float val = __expf(scores[i] - decf(segmax[s]));
        // segmented suffix-sum over equal-seg runs
        #pragma unroll
        for (int off = 1; off <= 32; off <<= 1) {
            float ov = __shfl_down(val, off, 64);
            int   os = __shfl_down(s, off, 64);
            if (lane + off < 64 && os == s) val += ov;
        }
        int prev = __shfl_up(s, 1, 64);
        if (lane == 0 || prev != s) atomicAdd(segsum + s, val);
    }
}

// K3: h[s,:] += p_i * emb[i,:], p computed inline. 32-lane group owns a
// 64-element contiguous chunk; lane l owns dims [4l,4l+4) as float4.
// Flush on segment change via atomicAdd (covers chunk-boundary segments).
__global__ __launch_bounds__(256) void k_wsum(
        const float* __restrict__ emb, const int* __restrict__ seg,
        const float* __restrict__ scores, const unsigned* __restrict__ segmax,
        const float* __restrict__ segsum, float* __restrict__ out) {
    const int lane = threadIdx.x & 31;
    const int g = blockIdx.x * 8 + (threadIdx.x >> 5);
    if (g >= N_ELEM / WCH) return;
    const int base = g * WCH;
    const float4* emb4 = reinterpret_cast<const float4*>(emb);

    int cur = seg[base];
    float m   = decf(segmax[cur]);
    float inv = 1.0f / segsum[cur];
    float4 acc = {0.f, 0.f, 0.f, 0.f};

    #define FLUSH() do { \
        float* o = out + (size_t)cur * D + lane * 4; \
        atomicAdd(o + 0, acc.x); atomicAdd(o + 1, acc.y); \
        atomicAdd(o + 2, acc.z); atomicAdd(o + 3, acc.w); \
    } while (0)
    #define STEP(SS, CC, VV) do { \
        if (SS != cur) { \
            FLUSH(); \
            acc.x = acc.y = acc.z = acc.w = 0.f; \
            cur = SS; m = decf(segmax[cur]); inv = 1.0f / segsum[cur]; \
        } \
        float p = __expf(CC - m) * inv; \
        acc.x = fmaf(p, VV.x, acc.x); acc.y = fmaf(p, VV.y, acc.y); \
        acc.z = fmaf(p, VV.z, acc.z); acc.w = fmaf(p, VV.w, acc.w); \
    } while (0)

    for (int e = base; e < base + WCH; e += 4) {
        int   ss0 = seg[e],     ss1 = seg[e + 1], ss2 = seg[e + 2], ss3 = seg[e + 3];
        float c0  = scores[e],  c1  = scores[e + 1], c2 = scores[e + 2], c3 = scores[e + 3];
        float4 v0 = emb4[(size_t)(e + 0) * 32 + lane];
        float4 v1 = emb4[(size_t)(e + 1) * 32 + lane];
        float4 v2 = emb4[(size_t)(e + 2) * 32 + lane];
        float4 v3 = emb4[(size_t)(e + 3) * 32 + lane];
        STEP(ss0, c0, v0);
        STEP(ss1, c1, v1);
        STEP(ss2, c2, v2);
        STEP(ss3, c3, v3);
    }
    FLUSH();
    #undef STEP
    #undef FLUSH
}

// K4: out[s,:] = h[s,:] @ w_out^T, in place per 128-row tile.
// LDS-staged, transposed with +4 padding to dodge bank conflicts.
#define PAD 132
__global__ __launch_bounds__(256) void k_proj(
        float* __restrict__ out, const float* __restrict__ wout) {
    __shared__ float As[128 * PAD];  // As[k*PAD + r] = h[r0+r][k]
    __shared__ float Bs[128 * PAD];  // Bs[k*PAD + j] = wout[j][k]
    const int tid = threadIdx.x;
    const int r0 = blockIdx.x * 128;
    for (int idx = tid; idx < 128 * 128; idx += 256) {
        int a = idx >> 7, k = idx & 127;
        As[k * PAD + a] = out[(size_t)(r0 + a) * D + k];
        Bs[k * PAD + a] = wout[(size_t)a * D + k];
    }
    __syncthreads();
    const int tx = tid & 15, ty = tid >> 4;
    const int rr = ty * 8, cc = tx * 8;
    float acc[8][8] = {};
    for (int k = 0; k < 128; ++k) {
        float a[8], b[8];
        *reinterpret_cast<float4*>(&a[0]) = *reinterpret_cast<const float4*>(&As[k * PAD + rr]);
        *reinterpret_cast<float4*>(&a[4]) = *reinterpret_cast<const float4*>(&As[k * PAD + rr + 4]);
        *reinterpret_cast<float4*>(&b[0]) = *reinterpret_cast<const float4*>(&Bs[k * PAD + cc]);
        *reinterpret_cast<float4*>(&b[4]) = *reinterpret_cast<const float4*>(&Bs[k * PAD + cc + 4]);
        #pragma unroll
        for (int i = 0; i < 8; ++i)
            #pragma unroll
            for (int j = 0; j < 8; ++j)
                acc[i][j] = fmaf(a[i], b[j], acc[i][j]);
    }
    #pragma unroll
    for (int i = 0; i < 8; ++i) {
        float4 o0 = {acc[i][0], acc[i][1], acc[i][2], acc[i][3]};
        float4 o1 = {acc[i][4], acc[i][5], acc[i][6], acc[i][7]};
        *reinterpret_cast<float4*>(&out[(size_t)(r0 + rr + i) * D + cc])     = o0;
        *reinterpret_cast<float4*>(&out[(size_t)(r0 + rr + i) * D + cc + 4]) = o1;
    }
}

extern "C" void kernel_launch(void* const* d_in, const int* in_sizes, int n_in,
                              void* d_out, int out_size, void* d_ws, size_t ws_size,
                              hipStream_t stream) {
    const float* emb  = (const float*)d_in[0];
    const int*   seg  = (const int*)d_in[1];
    const float* watt = (const float*)d_in[3];
    const float* wout = (const float*)d_in[4];
    float* out = (float*)d_out;

    // Workspace layout: scores[N] f32 | segmax[S] u32 | segsum[S] f32  (~4.5 MB)
    float*    scores = (float*)d_ws;
    unsigned* segmax = (unsigned*)((char*)d_ws + (size_t)N_ELEM * 4);
    float*    segsum = (float*)((char*)d_ws + (size_t)N_ELEM * 4 + (size_t)S_SEG * 4);

    k_zero<<<128, 256, 0, stream>>>((float4*)segmax, (2 * S_SEG) / 4);
    k_zero<<<2048, 256, 0, stream>>>((float4*)out, (S_SEG * D) / 4);

    k_scores<<<2048, 256, 0, stream>>>(emb, seg, watt, scores, segmax);
    k_sumexp<<<2048, 256, 0, stream>>>(scores, seg, segmax, segsum);
    const int n_groups = N_ELEM / WCH;                       // 15625
    k_wsum  <<<(n_groups + 7) / 8, 256, 0, stream>>>(emb, seg, scores, segmax, segsum, out);
    k_proj  <<<S_SEG / 128, 256, 0, stream>>>(out, wout);
}

// Round 4
// 263.822 us; speedup vs baseline: 1.4369x; 1.2779x over previous
//
#include <hip/hip_runtime.h>
#include <hip/hip_bf16.h>

#define N_ELEM 1000000
#define D 128
#define S_SEG 65536
#define SEGW 8            // segments per wave: NBLK*4 waves * SEGW == S_SEG
#define NBLK 2048
#define MAXSEG 192        // LDS score slots per wave; larger segments recompute (never hit in practice)

// Full 64-lane sum reduction; result valid in all lanes.
__device__ __forceinline__ float waveReduceSum(float d) {
    #pragma unroll
    for (int off = 1; off <= 32; off <<= 1)
        d += __shfl_xor(d, off, 64);
    return d;
}

// K1: off[s] = lower_bound(seg, s) over the SORTED map; off[S]=N.
__global__ __launch_bounds__(256) void k_bounds(const int* __restrict__ seg,
                                                int* __restrict__ off) {
    int s = blockIdx.x * blockDim.x + threadIdx.x;
    if (s > S_SEG) return;
    int lo = 0, hi = N_ELEM;
    while (lo < hi) {
        int mid = (lo + hi) >> 1;
        if (seg[mid] < s) lo = mid + 1; else hi = mid;
    }
    off[s] = lo;
}

// K2: one wave owns SEGW consecutive segments. Per segment:
//   pass A: stream rows, score = emb.w_att (64-lane reduce), online (m,l),
//           scores cached in LDS;
//   pass B: re-read rows (L1/L2/L3-hot, ~8KB gap), h = sum p*row, direct store.
// No atomics, no zero-init, emb touches HBM exactly once.
__global__ __launch_bounds__(256) void k_fused(
        const float* __restrict__ emb, const int* __restrict__ off,
        const float* __restrict__ watt, float* __restrict__ out) {
    __shared__ float sc[4][MAXSEG];
    const int lane = threadIdx.x & 63;
    const int w    = threadIdx.x >> 6;
    const int wid  = blockIdx.x * 4 + w;
    const float2 wv = reinterpret_cast<const float2*>(watt)[lane];
    const float2* emb2 = reinterpret_cast<const float2*>(emb);
    float2* out2 = reinterpret_cast<float2*>(out);

    const int s0 = wid * SEGW;
    for (int s = s0; s < s0 + SEGW; ++s) {
        const int beg = off[s], end = off[s + 1];
        float m = -__builtin_inff(), l = 0.f;
        for (int e = beg; e < end; ++e) {
            float2 v = emb2[(size_t)e * 64 + lane];
            float d = waveReduceSum(fmaf(v.x, wv.x, v.y * wv.y));
            int idx = e - beg;
            if (lane == 0 && idx < MAXSEG) sc[w][idx] = d;
            float mn = fmaxf(m, d);
            l = l * __expf(m - mn) + __expf(d - mn);
            m = mn;
        }
        const float inv = 1.0f / l;          // unused if segment empty
        float2 acc = {0.f, 0.f};
        for (int e = beg; e < end; ++e) {
            int idx = e - beg;
            float2 v = emb2[(size_t)e * 64 + lane];   // cache hit (just read in pass A)
            float d = (idx < MAXSEG) ? sc[w][idx]
                                     : waveReduceSum(fmaf(v.x, wv.x, v.y * wv.y));
            float p = __expf(d - m) * inv;
            acc.x = fmaf(p, v.x, acc.x);
            acc.y = fmaf(p, v.y, acc.y);
        }
        out2[(size_t)s * 64 + lane] = acc;   // empty segment -> zeros (required)
    }
}

// K3: out[s,:] = h[s,:] @ w_out^T, in place per 128-row tile.
// LDS-staged, transposed with +4 padding to dodge bank conflicts.
#define PAD 132
__global__ __launch_bounds__(256) void k_proj(
        float* __restrict__ out, const float* __restrict__ wout) {
    __shared__ float As[128 * PAD];  // As[k*PAD + r] = h[r0+r][k]
    __shared__ float Bs[128 * PAD];  // Bs[k*PAD + j] = wout[j][k]
    const int tid = threadIdx.x;
    const int r0 = blockIdx.x * 128;
    for (int idx = tid; idx < 128 * 128; idx += 256) {
        int a = idx >> 7, k = idx & 127;
        As[k * PAD + a] = out[(size_t)(r0 + a) * D + k];
        Bs[k * PAD + a] = wout[(size_t)a * D + k];
    }
    __syncthreads();
    const int tx = tid & 15, ty = tid >> 4;
    const int rr = ty * 8, cc = tx * 8;
    float acc[8][8] = {};
    for (int k = 0; k < 128; ++k) {
        float a[8], b[8];
        *reinterpret_cast<float4*>(&a[0]) = *reinterpret_cast<const float4*>(&As[k * PAD + rr]);
        *reinterpret_cast<float4*>(&a[4]) = *reinterpret_cast<const float4*>(&As[k * PAD + rr + 4]);
        *reinterpret_cast<float4*>(&b[0]) = *reinterpret_cast<const float4*>(&Bs[k * PAD + cc]);
        *reinterpret_cast<float4*>(&b[4]) = *reinterpret_cast<const float4*>(&Bs[k * PAD + cc + 4]);
        #pragma unroll
        for (int i = 0; i < 8; ++i)
            #pragma unroll
            for (int j = 0; j < 8; ++j)
                acc[i][j] = fmaf(a[i], b[j], acc[i][j]);
    }
    #pragma unroll
    for (int i = 0; i < 8; ++i) {
        float4 o0 = {acc[i][0], acc[i][1], acc[i][2], acc[i][3]};
        float4 o1 = {acc[i][4], acc[i][5], acc[i][6], acc[i][7]};
        *reinterpret_cast<float4*>(&out[(size_t)(r0 + rr + i) * D + cc])     = o0;
        *reinterpret_cast<float4*>(&out[(size_t)(r0 + rr + i) * D + cc + 4]) = o1;
    }
}

extern "C" void kernel_launch(void* const* d_in, const int* in_sizes, int n_in,
                              void* d_out, int out_size, void* d_ws, size_t ws_size,
                              hipStream_t stream) {
    const float* emb  = (const float*)d_in[0];
    const int*   seg  = (const int*)d_in[1];
    const float* watt = (const float*)d_in[3];
    const float* wout = (const float*)d_in[4];
    float* out = (float*)d_out;

    int* off = (int*)d_ws;   // (S_SEG+1) ints

    k_bounds<<<(S_SEG + 256) / 256, 256, 0, stream>>>(seg, off);
    k_fused <<<NBLK, 256, 0, stream>>>(emb, off, watt, out);
    k_proj  <<<S_SEG / 128, 256, 0, stream>>>(out, wout);
}

// Round 5
// 179.686 us; speedup vs baseline: 2.1097x; 1.4682x over previous
//
#include <hip/hip_runtime.h>
#include <hip/hip_bf16.h>

#define N_ELEM 1000000
#define D 128
#define S_SEG 65536
#define SEGW 8            // segments per wave: NBLK*4 waves * SEGW == S_SEG
#define NBLK 2048
#define NEG_BIG (-1e30f)

// K1: off[s] = lower_bound(seg, s) over the SORTED map; off[S]=N.
__global__ __launch_bounds__(256) void k_bounds(const int* __restrict__ seg,
                                                int* __restrict__ off) {
    int s = blockIdx.x * blockDim.x + threadIdx.x;
    if (s > S_SEG) return;
    int lo = 0, hi = N_ELEM;
    while (lo < hi) {
        int mid = (lo + hi) >> 1;
        if (seg[mid] < s) lo = mid + 1; else hi = mid;
    }
    off[s] = lo;
}

// 32-lane xor-reduce (offsets 1..16 never cross the 32-lane half).
__device__ __forceinline__ float halfReduce(float d) {
    #pragma unroll
    for (int off = 1; off <= 16; off <<= 1)
        d += __shfl_xor(d, off, 64);
    return d;
}

// One online-softmax step: state (m,l,a) absorbs (d, v). valid==false => no-op
// (branchless: p forced 0, m unchanged, scale = exp(0) = 1).
__device__ __forceinline__ void osm_step(float& m, float& l, float4& a,
                                         float d, float4 v, bool valid) {
    float mn = valid ? fmaxf(m, d) : m;
    float scale = __expf(m - mn);           // finite-finite: no NaN; underflows to 0
    float p = valid ? __expf(d - mn) : 0.f;
    m = mn;
    l = fmaf(l, scale, p);
    a.x = fmaf(a.x, scale, p * v.x);
    a.y = fmaf(a.y, scale, p * v.y);
    a.z = fmaf(a.z, scale, p * v.z);
    a.w = fmaf(a.w, scale, p * v.w);
}

// Merge state 2 into state 1.
__device__ __forceinline__ void osm_merge(float& m1, float& l1, float4& a1,
                                          float m2, float l2, float4 a2) {
    float m = fmaxf(m1, m2);
    float s1 = __expf(m1 - m), s2 = __expf(m2 - m);
    l1 = l1 * s1 + l2 * s2;
    a1.x = a1.x * s1 + a2.x * s2;
    a1.y = a1.y * s1 + a2.y * s2;
    a1.z = a1.z * s1 + a2.z * s2;
    a1.w = a1.w * s1 + a2.w * s2;
    m1 = m;
}

// K2: one wave owns SEGW consecutive segments; SINGLE streaming pass.
// float4/lane, 2 rows per load (lanes<32: row e, lanes>=32: row e+1).
// Two independent online states per half (unroll x2 -> 2 loads in flight).
// emb read from HBM exactly once; h written once; no atomics, no zero-init.
__global__ __launch_bounds__(256) void k_fused(
        const float* __restrict__ emb, const int* __restrict__ off,
        const float* __restrict__ watt, float* __restrict__ out) {
    const int lane = threadIdx.x & 63;
    const int half = lane >> 5;          // row parity this lane covers
    const int hl   = lane & 31;          // lane within half: dims 4*hl..4*hl+3
    const int wid  = blockIdx.x * 4 + (threadIdx.x >> 6);
    const float4 wv = reinterpret_cast<const float4*>(watt)[hl];
    const float4* emb4 = reinterpret_cast<const float4*>(emb);
    float4* out4 = reinterpret_cast<float4*>(out);

    const int s0 = wid * SEGW;
    for (int s = s0; s < s0 + SEGW; ++s) {
        const int beg = off[s], end = off[s + 1];
        float  mA = NEG_BIG, lA = 0.f; float4 aA = {0.f, 0.f, 0.f, 0.f};
        float  mB = NEG_BIG, lB = 0.f; float4 aB = {0.f, 0.f, 0.f, 0.f};
        int e = beg;
        for (; e + 4 <= end; e += 4) {
            float4 v0 = emb4[(size_t)(e + half) * 32 + hl];
            float4 v1 = emb4[(size_t)(e + 2 + half) * 32 + hl];
            float d0 = halfReduce(fmaf(v0.x, wv.x, fmaf(v0.y, wv.y, fmaf(v0.z, wv.z, v0.w * wv.w))));
            float d1 = halfReduce(fmaf(v1.x, wv.x, fmaf(v1.y, wv.y, fmaf(v1.z, wv.z, v1.w * wv.w))));
            osm_step(mA, lA, aA, d0, v0, true);
            osm_step(mB, lB, aB, d1, v1, true);
        }
        for (; e < end; e += 2) {
            bool valid = (e + half) < end;
            int r = valid ? (e + half) : (end - 1);      // safe in-bounds dummy
            float4 v = emb4[(size_t)r * 32 + hl];
            float d = halfReduce(fmaf(v.x, wv.x, fmaf(v.y, wv.y, fmaf(v.z, wv.z, v.w * wv.w))));
            osm_step(mA, lA, aA, valid ? d : NEG_BIG, v, valid);
        }
        // merge B into A, then cross-half merge via shfl_xor(32)
        osm_merge(mA, lA, aA, mB, lB, aB);
        float  mo = __shfl_xor(mA, 32, 64);
        float  lo = __shfl_xor(lA, 32, 64);
        float4 ao;
        ao.x = __shfl_xor(aA.x, 32, 64);
        ao.y = __shfl_xor(aA.y, 32, 64);
        ao.z = __shfl_xor(aA.z, 32, 64);
        ao.w = __shfl_xor(aA.w, 32, 64);
        osm_merge(mA, lA, aA, mo, lo, ao);
        float inv = (lA > 0.f) ? 1.0f / lA : 0.f;        // empty segment -> zeros
        if (half == 0) {
            float4 r = {aA.x * inv, aA.y * inv, aA.z * inv, aA.w * inv};
            out4[(size_t)s * 32 + hl] = r;
        }
    }
}

// K3: out[s,:] = h[s,:] @ w_out^T, in place per 128-row tile.
// LDS-staged, transposed with +4 padding to dodge bank conflicts.
#define PAD 132
__global__ __launch_bounds__(256) void k_proj(
        float* __restrict__ out, const float* __restrict__ wout) {
    __shared__ float As[128 * PAD];  // As[k*PAD + r] = h[r0+r][k]
    __shared__ float Bs[128 * PAD];  // Bs[k*PAD + j] = wout[j][k]
    const int tid = threadIdx.x;
    const int r0 = blockIdx.x * 128;
    for (int idx = tid; idx < 128 * 128; idx += 256) {
        int a = idx >> 7, k = idx & 127;
        As[k * PAD + a] = out[(size_t)(r0 + a) * D + k];
        Bs[k * PAD + a] = wout[(size_t)a * D + k];
    }
    __syncthreads();
    const int tx = tid & 15, ty = tid >> 4;
    const int rr = ty * 8, cc = tx * 8;
    float acc[8][8] = {};
    for (int k = 0; k < 128; ++k) {
        float a[8], b[8];
        *reinterpret_cast<float4*>(&a[0]) = *reinterpret_cast<const float4*>(&As[k * PAD + rr]);
        *reinterpret_cast<float4*>(&a[4]) = *reinterpret_cast<const float4*>(&As[k * PAD + rr + 4]);
        *reinterpret_cast<float4*>(&b[0]) = *reinterpret_cast<const float4*>(&Bs[k * PAD + cc]);
        *reinterpret_cast<float4*>(&b[4]) = *reinterpret_cast<const float4*>(&Bs[k * PAD + cc + 4]);
        #pragma unroll
        for (int i = 0; i < 8; ++i)
            #pragma unroll
            for (int j = 0; j < 8; ++j)
                acc[i][j] = fmaf(a[i], b[j], acc[i][j]);
    }
    #pragma unroll
    for (int i = 0; i < 8; ++i) {
        float4 o0 = {acc[i][0], acc[i][1], acc[i][2], acc[i][3]};
        float4 o1 = {acc[i][4], acc[i][5], acc[i][6], acc[i][7]};
        *reinterpret_cast<float4*>(&out[(size_t)(r0 + rr + i) * D + cc])     = o0;
        *reinterpret_cast<float4*>(&out[(size_t)(r0 + rr + i) * D + cc + 4]) = o1;
    }
}

extern "C" void kernel_launch(void* const* d_in, const int* in_sizes, int n_in,
                              void* d_out, int out_size, void* d_ws, size_t ws_size,
                              hipStream_t stream) {
    const float* emb  = (const float*)d_in[0];
    const int*   seg  = (const int*)d_in[1];
    const float* watt = (const float*)d_in[3];
    const float* wout = (const float*)d_in[4];
    float* out = (float*)d_out;

    int* off = (int*)d_ws;   // (S_SEG+1) ints

    k_bounds<<<(S_SEG + 256) / 256, 256, 0, stream>>>(seg, off);
    k_fused <<<NBLK, 256, 0, stream>>>(emb, off, watt, out);
    k_proj  <<<S_SEG / 128, 256, 0, stream>>>(out, wout);
}